// Round 3
// baseline (265.844 us; speedup 1.0000x reference)
//
#include <hip/hip_runtime.h>
#include <hip/hip_bf16.h>
#include <stdint.h>

#define HH 7
#define NMID 19
#define RPT 4          // rows per thread
#define BLOCK 256

typedef _Float16 half2_t __attribute__((ext_vector_type(2)));

__device__ __forceinline__ uint32_t pack_h2(float a, float b) {
    return __builtin_bit_cast(uint32_t, __builtin_amdgcn_cvt_pkrtz(a, b));
}

// ---------------------------------------------------------------------------
// d_ws layout (uint32 units):
//   [0..7]            fc1 W packed half2 per row j: {W1[j,0], W1[j,1]}, row 7 = 0
//   [8..15]           b1 as f32 (8, pad 0)
//   [16 .. 16+608)    mid W: layer l, row j(0..7), pair p(0..3):
//                     half2 {Wm[l,j,2p], Wm[l,j,2p+1]}; k=7 and row 7 zeroed
//   [624 .. 624+152)  mid bias f32, 8 per layer (pad 0)
//   [776..783]        Wo packed: row r(0..1) x pair p(0..3)
//   [784..785]        bo f32
// Total 786 dwords = 3144 bytes. All entries written every call (ws is
// re-poisoned to 0xAA before each launch).
// ---------------------------------------------------------------------------

__global__ void prep_kernel(const float* __restrict__ W1, const float* __restrict__ b1,
                            const float* __restrict__ Wm, const float* __restrict__ bm,
                            const float* __restrict__ Wo, const float* __restrict__ bo,
                            uint32_t* __restrict__ ws)
{
    const int t = threadIdx.x;
    float* wsf = (float*)ws;

    if (t < 8) {
        // fc1 weights (K=2 fits one half2)
        float w0 = (t < HH) ? W1[t * 2 + 0] : 0.f;
        float w1 = (t < HH) ? W1[t * 2 + 1] : 0.f;
        ws[t] = pack_h2(w0, w1);
        wsf[8 + t] = (t < HH) ? b1[t] : 0.f;

        // Wo packed: 2 rows x 4 pairs
        int r = t >> 2, p = t & 3;
        int k0 = 2 * p, k1 = 2 * p + 1;
        float o0 = (k0 < HH) ? Wo[r * HH + k0] : 0.f;
        float o1 = (k1 < HH) ? Wo[r * HH + k1] : 0.f;
        ws[776 + t] = pack_h2(o0, o1);
    }
    if (t < 2) wsf[784 + t] = bo[t];

    // mid weights: 19 layers x 8 rows x 4 pairs = 608 entries
    for (int e = t; e < NMID * 8 * 4; e += BLOCK) {
        int l = e >> 5;
        int j = (e >> 2) & 7;
        int p = e & 3;
        float w0 = 0.f, w1 = 0.f;
        if (j < HH) {
            int k0 = 2 * p, k1 = 2 * p + 1;
            if (k0 < HH) w0 = Wm[(l * HH + j) * HH + k0];
            if (k1 < HH) w1 = Wm[(l * HH + j) * HH + k1];
        }
        ws[16 + e] = pack_h2(w0, w1);
    }
    // mid bias: 19 x 8
    for (int e = t; e < NMID * 8; e += BLOCK) {
        int l = e >> 3, j = e & 7;
        wsf[624 + e] = (j < HH) ? bm[l * HH + j] : 0.f;
    }
}

__device__ __forceinline__ float elu_f32(float a) {
    return (a > 0.f) ? a : (__expf(a) - 1.f);
}

__device__ __forceinline__ half2_t as_h2(uint32_t u) {
    return __builtin_bit_cast(half2_t, u);
}

__global__ __launch_bounds__(BLOCK) void net_main(
    const float* __restrict__ x,
    const uint32_t* __restrict__ ws,
    float* __restrict__ out, int nthreads)
{
    const int t = blockIdx.x * blockDim.x + threadIdx.x;
    const int stride = nthreads;  // rows handled: t + u*stride, u in [0,RPT)
    const float* __restrict__ wsf = (const float*)ws;

    // ---- load inputs (coalesced float2) ----
    float2 xin[RPT];
#pragma unroll
    for (int u = 0; u < RPT; ++u)
        xin[u] = reinterpret_cast<const float2*>(x)[t + u * stride];

    uint32_t h[RPT][4];  // hidden state as 4 packed half2 per row (elem 7 == 0)

    // ---- fc1 + ELU ----
#pragma unroll
    for (int u = 0; u < RPT; ++u) {
        uint32_t xv = pack_h2(xin[u].x, xin[u].y);
        float e[HH];
#pragma unroll
        for (int j = 0; j < HH; ++j) {
            float a = __builtin_amdgcn_fdot2(as_h2(xv), as_h2(ws[j]), wsf[8 + j], false);
            e[j] = elu_f32(a);
        }
        h[u][0] = pack_h2(e[0], e[1]);
        h[u][1] = pack_h2(e[2], e[3]);
        h[u][2] = pack_h2(e[4], e[5]);
        h[u][3] = pack_h2(e[6], 0.f);
    }

    // ---- fc2..fc20: 19 x (Linear(7,7) + ELU), dot2 f16 with f32 accum ----
#pragma unroll
    for (int l = 0; l < NMID; ++l) {
        const uint32_t* __restrict__ wl = ws + 16 + l * 32;
        const float* __restrict__ bl = wsf + 624 + l * 8;
#pragma unroll
        for (int u = 0; u < RPT; ++u) {
            float e[HH];
#pragma unroll
            for (int j = 0; j < HH; ++j) {
                float acc = bl[j];
#pragma unroll
                for (int p = 0; p < 4; ++p)
                    acc = __builtin_amdgcn_fdot2(as_h2(h[u][p]), as_h2(wl[j * 4 + p]), acc, false);
                e[j] = elu_f32(acc);
            }
            h[u][0] = pack_h2(e[0], e[1]);
            h[u][1] = pack_h2(e[2], e[3]);
            h[u][2] = pack_h2(e[4], e[5]);
            h[u][3] = pack_h2(e[6], 0.f);
        }
    }

    // ---- fc21 + log_softmax(2) ----
#pragma unroll
    for (int u = 0; u < RPT; ++u) {
        float l0 = wsf[784], l1 = wsf[785];
#pragma unroll
        for (int p = 0; p < 4; ++p) {
            l0 = __builtin_amdgcn_fdot2(as_h2(h[u][p]), as_h2(ws[776 + p]), l0, false);
            l1 = __builtin_amdgcn_fdot2(as_h2(h[u][p]), as_h2(ws[776 + 4 + p]), l1, false);
        }
        float m = fmaxf(l0, l1);
        float z = m + __logf(__expf(l0 - m) + __expf(l1 - m));
        float2 o; o.x = l0 - z; o.y = l1 - z;
        reinterpret_cast<float2*>(out)[t + u * stride] = o;
    }
}

extern "C" void kernel_launch(void* const* d_in, const int* in_sizes, int n_in,
                              void* d_out, int out_size, void* d_ws, size_t ws_size,
                              hipStream_t stream) {
    const float* x  = (const float*)d_in[0];
    const float* W1 = (const float*)d_in[1];
    const float* b1 = (const float*)d_in[2];
    const float* Wm = (const float*)d_in[3];
    const float* bm = (const float*)d_in[4];
    const float* Wo = (const float*)d_in[5];
    const float* bo = (const float*)d_in[6];
    float* out = (float*)d_out;
    uint32_t* ws = (uint32_t*)d_ws;

    const int B = in_sizes[0] / 2;            // x is [B,2]
    const int nthreads = B / RPT;             // 4194304/4 = 1048576
    const int grid = nthreads / BLOCK;        // 4096

    prep_kernel<<<1, BLOCK, 0, stream>>>(W1, b1, Wm, bm, Wo, bo, ws);
    net_main<<<grid, BLOCK, 0, stream>>>(x, ws, out, nthreads);
}